// Round 1
// baseline (798.026 us; speedup 1.0000x reference)
//
#include <hip/hip_runtime.h>
#include <cstdint>
#include <cstddef>

// ---------------------------------------------------------------------------
// DifferentialAttention on MI355X (gfx950), bf16 MFMA pipeline.
// B=2 T=2048 D=2048 H=16 HD=128 HHD=64  SCALE=1/8
// Pipeline: f32->bf16 converts / weight transposes, 4x gemm_bt (m97-style),
// flash attention with dual online softmax (scores over first/second 64 dims).
// ---------------------------------------------------------------------------

typedef unsigned short u16;
typedef __bf16 bf16x8 __attribute__((ext_vector_type(8)));
typedef float f32x4 __attribute__((ext_vector_type(4)));

#define LOG2E 1.44269504088896340736f
#define SCALE 0.125f

__device__ __forceinline__ u16 f2bu(float f) {
  unsigned int x = __float_as_uint(f);
  x += 0x7fffu + ((x >> 16) & 1u);   // round-to-nearest-even (finite inputs)
  return (u16)(x >> 16);
}

// global -> LDS staging, 16B per lane. lds_uniform must be wave-uniform;
// hardware (or fallback) places lane's data at lds_uniform + lane*16.
__device__ __forceinline__ void stage16(const void* g, void* lds_uniform, int lane) {
#if defined(__has_builtin) && __has_builtin(__builtin_amdgcn_global_load_lds)
  (void)lane;
  __builtin_amdgcn_global_load_lds(
      (__attribute__((address_space(1))) void*)(g),
      (__attribute__((address_space(3))) void*)(lds_uniform), 16, 0, 0);
#else
  *(uint4*)((char*)lds_uniform + lane * 16) = *(const uint4*)g;
#endif
}

// ---------------------------------------------------------------------------
// fp32 -> bf16 elementwise (vectorized), exact-grid
// ---------------------------------------------------------------------------
__global__ void f32_to_bf16_k(const float* __restrict__ in, u16* __restrict__ out, int n4) {
  int i = blockIdx.x * blockDim.x + threadIdx.x;
  if (i < n4) {
    float4 v = ((const float4*)in)[i];
    ushort4 u;
    u.x = f2bu(v.x); u.y = f2bu(v.y); u.z = f2bu(v.z); u.w = f2bu(v.w);
    ((ushort4*)out)[i] = u;
  }
}

// ---------------------------------------------------------------------------
// fp32 (R x C) -> bf16 transposed (C x R), 32x32 LDS tiles
// ---------------------------------------------------------------------------
__global__ void transpose_f32_bf16(const float* __restrict__ in, u16* __restrict__ out,
                                   int R, int C) {
  __shared__ u16 tile[32][33];
  const int tx = threadIdx.x & 31, ty = threadIdx.x >> 5; // 32 x 8
  const int c0 = blockIdx.x * 32, r0 = blockIdx.y * 32;
#pragma unroll
  for (int i = 0; i < 32; i += 8)
    tile[ty + i][tx] = f2bu(in[(size_t)(r0 + ty + i) * C + c0 + tx]);
  __syncthreads();
#pragma unroll
  for (int i = 0; i < 32; i += 8)
    out[(size_t)(c0 + ty + i) * R + r0 + tx] = tile[tx][ty + i];
}

// ---------------------------------------------------------------------------
// C(M,N) = A(M,K) @ BT(N,K)^T   all bf16 in, fp32 accumulate.
// 128x128 tile, BK=32, 256 threads (4 waves 2x2, each 64x64 = 4x4 MFMA tiles)
// MODE 0: bf16 natural   MODE 1: fp32 natural
// MODE 2: bf16 V-transpose -> out[((b*16+h)*128+d)*2048 + t]
// ---------------------------------------------------------------------------
template <int MODE>
__global__ __launch_bounds__(256, 2)
void gemm_bt(const u16* __restrict__ A, const u16* __restrict__ BT,
             void* __restrict__ C, int Mdim, int Ndim, int Kdim) {
  __shared__ __align__(16) u16 As[128 * 32];
  __shared__ __align__(16) u16 Bs[128 * 32];
  const int tid = threadIdx.x;
  const int lane = tid & 63;
  const int w = tid >> 6;
  const int wm = w & 1, wn = w >> 1;
  const int li = lane & 15, lh = lane >> 4;
  const int m0 = blockIdx.x * 128;
  const int n0 = blockIdx.y * 128;

  const f32x4 fzero = {0.f, 0.f, 0.f, 0.f};
  f32x4 acc[4][4];
#pragma unroll
  for (int i = 0; i < 4; ++i)
#pragma unroll
    for (int jj = 0; jj < 4; ++jj) acc[i][jj] = fzero;

  for (int k0 = 0; k0 < Kdim; k0 += 32) {
    // stage A-tile (128x32) and BT-tile (128x32): 512 16B-chunks each, 4/row
#pragma unroll
    for (int i = 0; i < 2; ++i) {
      const int c = i * 256 + w * 64 + lane;
      stage16(A + (size_t)(m0 + (c >> 2)) * Kdim + k0 + ((c & 3) << 3),
              (char*)As + (size_t)(i * 256 + w * 64) * 16, lane);
      stage16(BT + (size_t)(n0 + (c >> 2)) * Kdim + k0 + ((c & 3) << 3),
              (char*)Bs + (size_t)(i * 256 + w * 64) * 16, lane);
    }
    __syncthreads();

    bf16x8 af[4], bfr[4];
#pragma unroll
    for (int mt = 0; mt < 4; ++mt)
      af[mt] = *(const bf16x8*)&As[(wm * 64 + mt * 16 + li) * 32 + lh * 8];
#pragma unroll
    for (int nt = 0; nt < 4; ++nt)
      bfr[nt] = *(const bf16x8*)&Bs[(wn * 64 + nt * 16 + li) * 32 + lh * 8];
#pragma unroll
    for (int mt = 0; mt < 4; ++mt)
#pragma unroll
      for (int nt = 0; nt < 4; ++nt)
        acc[mt][nt] = __builtin_amdgcn_mfma_f32_16x16x32_bf16(af[mt], bfr[nt], acc[mt][nt], 0, 0, 0);
    __syncthreads();
  }

  // epilogue: C/D layout col = lane&15, row = (lane>>4)*4 + reg
#pragma unroll
  for (int mt = 0; mt < 4; ++mt) {
#pragma unroll
    for (int nt = 0; nt < 4; ++nt) {
      const int mb = m0 + wm * 64 + mt * 16 + lh * 4; // 4 consecutive rows
      const int n = n0 + wn * 64 + nt * 16 + li;
      if (MODE == 0) {
        u16* o = (u16*)C;
#pragma unroll
        for (int r = 0; r < 4; ++r)
          o[(size_t)(mb + r) * Ndim + n] = f2bu(acc[mt][nt][r]);
      } else if (MODE == 1) {
        float* o = (float*)C;
#pragma unroll
        for (int r = 0; r < 4; ++r)
          o[(size_t)(mb + r) * Ndim + n] = acc[mt][nt][r];
      } else {
        u16* o = (u16*)C;
        const int bb = mb >> 11, t = mb & 2047;
        const int hh = n >> 7, d = n & 127;
        ushort4 u;
        u.x = f2bu(acc[mt][nt][0]);
        u.y = f2bu(acc[mt][nt][1]);
        u.z = f2bu(acc[mt][nt][2]);
        u.w = f2bu(acc[mt][nt][3]);
        *(ushort4*)&o[((size_t)((bb * 16 + hh) * 128 + d) << 11) + t] = u;
      }
    }
  }
}

// ---------------------------------------------------------------------------
// Flash differential attention.
// grid (T/64, H, B), 256 threads = 4 waves, wave w owns Q rows t0+w*16..+15.
// Q frags register-resident; K/V B-frags loaded directly from global (16B/lane
// contiguous); P transits LDS with xor-block swizzle (C-layout -> A-layout).
// Dual online softmax: O = O1/l1 - sigmoid(lam)*O2/l2.
// ---------------------------------------------------------------------------
__global__ __launch_bounds__(256, 2)
void diff_attn(const u16* __restrict__ Q, const u16* __restrict__ K,
               const u16* __restrict__ VT, const float* __restrict__ lamin,
               u16* __restrict__ AO) {
  __shared__ __align__(16) u16 Ps1[64 * 64];
  __shared__ __align__(16) u16 Ps2[64 * 64];

  const int tid = threadIdx.x, lane = tid & 63, w = tid >> 6;
  const int li = lane & 15, lh = lane >> 4;
  const int it = blockIdx.x, h = blockIdx.y, b = blockIdx.z;
  const int t0 = it * 64;

  const float lam = 1.f / (1.f + exp2f(-lamin[h] * LOG2E));

  // Q fragments: kk=0,1 -> first 64 dims (S1), kk=2,3 -> second 64 (S2)
  bf16x8 qf[4];
  {
    const u16* qp = Q + (size_t)(b * 2048 + t0 + w * 16 + li) * 2048 + h * 128 + lh * 8;
#pragma unroll
    for (int kk = 0; kk < 4; ++kk) qf[kk] = *(const bf16x8*)(qp + kk * 32);
  }

  const f32x4 fzero = {0.f, 0.f, 0.f, 0.f};
  f32x4 o1[8], o2[8];
#pragma unroll
  for (int i = 0; i < 8; ++i) { o1[i] = fzero; o2[i] = fzero; }
  float m1[4], l1[4], m2[4], l2[4];
#pragma unroll
  for (int r = 0; r < 4; ++r) {
    m1[r] = -__builtin_inff(); m2[r] = -__builtin_inff();
    l1[r] = 0.f; l2[r] = 0.f;
  }

  const u16* kp = K + ((size_t)(b * 2048)) * 2048 + h * 128;  // + s*2048 + c
  const u16* vp = VT + ((size_t)(b * 16 + h) << 18);          // + d*2048 + s

  for (int j = 0; j <= it; ++j) {
    // ---- S = Q @ K^T (two halves) ----
    f32x4 s1[4], s2[4];
#pragma unroll
    for (int nt = 0; nt < 4; ++nt) { s1[nt] = fzero; s2[nt] = fzero; }
#pragma unroll
    for (int nt = 0; nt < 4; ++nt) {
      const u16* kr = kp + (size_t)(j * 64 + nt * 16 + li) * 2048 + lh * 8;
      bf16x8 b0 = *(const bf16x8*)(kr);
      bf16x8 b1 = *(const bf16x8*)(kr + 32);
      bf16x8 b2 = *(const bf16x8*)(kr + 64);
      bf16x8 b3 = *(const bf16x8*)(kr + 96);
      s1[nt] = __builtin_amdgcn_mfma_f32_16x16x32_bf16(qf[0], b0, s1[nt], 0, 0, 0);
      s1[nt] = __builtin_amdgcn_mfma_f32_16x16x32_bf16(qf[1], b1, s1[nt], 0, 0, 0);
      s2[nt] = __builtin_amdgcn_mfma_f32_16x16x32_bf16(qf[2], b2, s2[nt], 0, 0, 0);
      s2[nt] = __builtin_amdgcn_mfma_f32_16x16x32_bf16(qf[3], b3, s2[nt], 0, 0, 0);
    }

    // ---- scale, causal mask, dual online softmax ----
    const bool diag = (j == it);
#pragma unroll
    for (int r = 0; r < 4; ++r) {
      const int tg = t0 + w * 16 + lh * 4 + r;
      float rmax1 = -__builtin_inff(), rmax2 = -__builtin_inff();
#pragma unroll
      for (int nt = 0; nt < 4; ++nt) {
        float v1 = s1[nt][r] * SCALE;
        float v2 = s2[nt][r] * SCALE;
        if (diag) {
          const int sg = j * 64 + nt * 16 + li;
          if (sg > tg) { v1 = -__builtin_inff(); v2 = -__builtin_inff(); }
        }
        s1[nt][r] = v1; s2[nt][r] = v2;
        rmax1 = fmaxf(rmax1, v1); rmax2 = fmaxf(rmax2, v2);
      }
#pragma unroll
      for (int off = 1; off < 16; off <<= 1) {
        rmax1 = fmaxf(rmax1, __shfl_xor(rmax1, off));
        rmax2 = fmaxf(rmax2, __shfl_xor(rmax2, off));
      }
      const float nm1 = fmaxf(m1[r], rmax1);
      const float nm2 = fmaxf(m2[r], rmax2);
      float rs1 = 0.f, rs2 = 0.f;
#pragma unroll
      for (int nt = 0; nt < 4; ++nt) {
        const float p1 = exp2f((s1[nt][r] - nm1) * LOG2E);
        const float p2 = exp2f((s2[nt][r] - nm2) * LOG2E);
        s1[nt][r] = p1; s2[nt][r] = p2;
        rs1 += p1; rs2 += p2;
      }
#pragma unroll
      for (int off = 1; off < 16; off <<= 1) {
        rs1 += __shfl_xor(rs1, off);
        rs2 += __shfl_xor(rs2, off);
      }
      const float a1 = exp2f((m1[r] - nm1) * LOG2E);  // 0 on first tile
      const float a2 = exp2f((m2[r] - nm2) * LOG2E);
      l1[r] = l1[r] * a1 + rs1;
      l2[r] = l2[r] * a2 + rs2;
      m1[r] = nm1; m2[r] = nm2;
#pragma unroll
      for (int nt = 0; nt < 8; ++nt) { o1[nt][r] *= a1; o2[nt][r] *= a2; }
    }

    __syncthreads();  // previous iteration's Ps reads complete

    // ---- write P (bf16) to LDS, xor-swizzled 8-elem blocks ----
#pragma unroll
    for (int nt = 0; nt < 4; ++nt) {
      const int cb = nt * 2 + (li >> 3);
#pragma unroll
      for (int r = 0; r < 4; ++r) {
        const int row = w * 16 + lh * 4 + r;
        const int idx = row * 64 + (cb ^ (row & 7)) * 8 + (li & 7);
        Ps1[idx] = f2bu(s1[nt][r]);
        Ps2[idx] = f2bu(s2[nt][r]);
      }
    }
    __syncthreads();  // Ps visible

    // ---- O += P @ V (V B-frags direct from global VT) ----
#pragma unroll
    for (int ks = 0; ks < 2; ++ks) {
      const int arow = w * 16 + li;
      const int jb = ((ks * 4 + lh) ^ (li & 7)) * 8;
      bf16x8 a1f = *(const bf16x8*)&Ps1[arow * 64 + jb];
      bf16x8 a2f = *(const bf16x8*)&Ps2[arow * 64 + jb];
#pragma unroll
      for (int nt = 0; nt < 8; ++nt) {
        const u16* vr = vp + (size_t)(nt * 16 + li) * 2048 + j * 64 + ks * 32 + lh * 8;
        bf16x8 vf = *(const bf16x8*)vr;
        o1[nt] = __builtin_amdgcn_mfma_f32_16x16x32_bf16(a1f, vf, o1[nt], 0, 0, 0);
        o2[nt] = __builtin_amdgcn_mfma_f32_16x16x32_bf16(a2f, vf, o2[nt], 0, 0, 0);
      }
    }
  }

  // ---- epilogue: O = O1/l1 - lam*O2/l2, bf16, layout (b, t, h*128 + d) ----
#pragma unroll
  for (int r = 0; r < 4; ++r) {
    const float inv1 = 1.f / l1[r];
    const float inv2 = lam / l2[r];
    u16* orow = AO + (size_t)(b * 2048 + t0 + w * 16 + lh * 4 + r) * 2048 + h * 128 + li;
#pragma unroll
    for (int nt = 0; nt < 8; ++nt)
      orow[nt * 16] = f2bu(o1[nt][r] * inv1 - o2[nt][r] * inv2);
  }
}

// ---------------------------------------------------------------------------
extern "C" void kernel_launch(void* const* d_in, const int* in_sizes, int n_in,
                              void* d_out, int out_size, void* d_ws, size_t ws_size,
                              hipStream_t stream) {
  const float* x   = (const float*)d_in[0];
  const float* Wq  = (const float*)d_in[1];
  const float* Wk  = (const float*)d_in[2];
  const float* Wv  = (const float*)d_in[3];
  const float* Wo  = (const float*)d_in[4];
  const float* lam = (const float*)d_in[5];
  float* out = (float*)d_out;

  const size_t MB = 1ull << 20;
  char* ws = (char*)d_ws;
  u16* xb = (u16*)(ws);             // 16 MB: x in bf16, reused later as AO
  u16* wT = (u16*)(ws + 16 * MB);   //  8 MB: current W^T bf16
  u16* vt = (u16*)(ws + 24 * MB);   // 16 MB: V^T per head (b,h,d,t)
  u16* qb = (u16*)d_out;            // 16 MB scratch inside d_out (rewritten at end)
  u16* kb = qb + (size_t)4096 * 2048;
  u16* ao = xb;                     // alias: xb dead after V projection

  // x -> bf16
  f32_to_bf16_k<<<8192, 256, 0, stream>>>(x, xb, 2097152);

  // Q = x @ Wq
  transpose_f32_bf16<<<dim3(64, 64), 256, 0, stream>>>(Wq, wT, 2048, 2048);
  gemm_bt<0><<<dim3(32, 16), 256, 0, stream>>>(xb, wT, qb, 4096, 2048, 2048);
  // K = x @ Wk
  transpose_f32_bf16<<<dim3(64, 64), 256, 0, stream>>>(Wk, wT, 2048, 2048);
  gemm_bt<0><<<dim3(32, 16), 256, 0, stream>>>(xb, wT, kb, 4096, 2048, 2048);
  // V = x @ Wv, stored transposed per head
  transpose_f32_bf16<<<dim3(64, 64), 256, 0, stream>>>(Wv, wT, 2048, 2048);
  gemm_bt<2><<<dim3(32, 16), 256, 0, stream>>>(xb, wT, vt, 4096, 2048, 2048);

  // flash differential attention
  diff_attn<<<dim3(32, 16, 2), 256, 0, stream>>>(qb, kb, vt, lam, ao);

  // out = AO @ Wo  (fp32 output)
  transpose_f32_bf16<<<dim3(64, 64), 256, 0, stream>>>(Wo, wT, 2048, 2048);
  gemm_bt<1><<<dim3(32, 16), 256, 0, stream>>>(ao, wT, out, 4096, 2048, 2048);
}